// Round 8
// baseline (139.206 us; speedup 1.0000x reference)
//
#include <hip/hip_runtime.h>
#include <math.h>

#define KMAX   32
#define CIN    64
#define COUT   64
#define NKERN  27
#define PPW    8          // points per wave
constexpr float BN_EPS = 1e-5f;

typedef _Float16 f16;
typedef _Float16 f16x2 __attribute__((ext_vector_type(2)));
typedef _Float16 f16x8 __attribute__((ext_vector_type(8)));

#if __has_builtin(__builtin_amdgcn_fdot2)
#define FDOT2(a, b, c) __builtin_amdgcn_fdot2((a), (b), (c), false)
#else
static __device__ inline float FDOT2(f16x2 a, f16x2 b, float c) {
    return fmaf((float)a.x, (float)b.x, fmaf((float)a.y, (float)b.y, c));
}
#endif

// ---------------- kernel 0: zero the stats accumulator ----------------
__global__ void k_zero(float* stats) {
    stats[threadIdx.x] = 0.0f;   // 128 threads: [0..63]=sum, [64..127]=sumsq
}

// ---------------- kernel A: convert inputs f32 -> f16 -----------------
__global__ __launch_bounds__(256) void k_cvt(const float* __restrict__ in,
                                             f16* __restrict__ out, int total4) {
    const int stride = gridDim.x * blockDim.x;
    for (int i = blockIdx.x * blockDim.x + threadIdx.x; i < total4; i += stride) {
        const float4 v = ((const float4*)in)[i];
        f16x2 a = { (f16)v.x, (f16)v.y };
        f16x2 b = { (f16)v.z, (f16)v.w };
        uint2 u;
        u.x = *(const unsigned int*)&a;
        u.y = *(const unsigned int*)&b;
        ((uint2*)out)[i] = u;
    }
}

// ---------------- kernel B: prep sw(f16), packed dw, zeros-row --------
// dwp layout: [c8][j][e], e=0..7 -> dw[8*c8+e][j], so lane j reads its
// column slice as one contiguous f16x8.
__global__ __launch_bounds__(256) void k_prep(const float* __restrict__ sw,
                                              const float* __restrict__ dw,
                                              f16* __restrict__ sw_h,
                                              f16* __restrict__ dwp,
                                              f16* __restrict__ zrow) {
    const int t = threadIdx.x;
    for (int i = t; i < NKERN * CIN; i += 256) sw_h[i] = (f16)sw[i];
    for (int i = t; i < 8 * COUT; i += 256) {           // (c8, j) pairs
        const int c8 = i >> 6, j = i & 63;
        #pragma unroll
        for (int e = 0; e < 8; ++e)
            dwp[(size_t)i * 8 + e] = (f16)dw[(8 * c8 + e) * COUT + j];
    }
    if (t < CIN) zrow[t] = (f16)0.0f;
}

// ---------------- kernel 1: gather-conv + 64x64 matmul + relu --------
// Wave-uniform n -> indices via s_load (SALU addressing). Invalid k maps
// to the zeros-row (L1-resident) via uniform select: no masks, no branch.
// sw read from L1 (f16); dw packed f16x8 in LDS, hoisted as loop-invariant.
__global__ __launch_bounds__(256, 4) void k_conv(
    const f16*   __restrict__ gh,          // f16[(N+1), 64], row N = zeros
    const f16*   __restrict__ swh,         // f16[27*64]
    const f16*   __restrict__ dwp,         // f16[8*64*8] packed
    const float* __restrict__ bias,        // [1, 64]
    const int*   __restrict__ nn_count,    // [N]
    const int*   __restrict__ nn_index,    // [N, 32]
    const int*   __restrict__ filt_index,  // [N, 32]
    float*       __restrict__ xout,        // [N, 64]  pre-BN (relu'd)
    float*       __restrict__ stats,       // [128]
    int zrowIdx)                           // = N
{
    __shared__ f16x8 dw_lds[8 * COUT];     // 8 KB
    __shared__ f16   sp_lds[4][CIN];       // 0.5 KB
    __shared__ float red[2][4][COUT];      // 2 KB

    const int tid = threadIdx.x;
    for (int i = tid; i < 512; i += 256)   // 8 KB = 512 x 16 B
        ((uint4*)dw_lds)[i] = ((const uint4*)dwp)[i];
    __syncthreads();

    const int wave = __builtin_amdgcn_readfirstlane(tid >> 6);
    const int lane = tid & 63;
    const float b = bias[lane];

    // loop-invariant dw column slices (no anchors: compiler keeps or re-reads)
    f16x8 dwr[8];
    #pragma unroll
    for (int c8 = 0; c8 < 8; ++c8) dwr[c8] = dw_lds[c8 * COUT + lane];

    const int base = blockIdx.x * (4 * PPW) + wave * PPW;
    float sum = 0.0f, sumsq = 0.0f;

    for (int p = 0; p < PPW; ++p) {
        const int n   = base + p;                       // wave-uniform
        const int cnt = nn_count[n];                    // s_load
        const int* __restrict__ ni = nn_index   + (size_t)n * KMAX;
        const int* __restrict__ fi = filt_index + (size_t)n * KMAX;

        float a0 = 0.f, a1 = 0.f, a2 = 0.f, a3 = 0.f;

        // two unconditional 16-batches: issue 16 g + 16 w, then 16 fma_mix
        #pragma unroll
        for (int h = 0; h < 2; ++h) {
            f16 g[16], w[16];
            #pragma unroll
            for (int k = 0; k < 16; ++k) {
                const int kk = 16 * h + k;
                const int rk = (kk < cnt) ? ni[kk] : zrowIdx;   // uniform sel
                g[k] = gh[(size_t)rk * CIN + lane];
                w[k] = swh[fi[kk] * CIN + lane];                // L1-resident
            }
            #pragma unroll
            for (int k = 0; k < 16; ++k) {
                const float gv = (float)g[k];
                const float wv = (float)w[k];
                float& a = (k & 3) == 0 ? a0 : (k & 3) == 1 ? a1
                         : (k & 3) == 2 ? a2 : a3;
                a = fmaf(gv, wv, a);                            // v_fma_mix
            }
        }
        const float spv = ((a0 + a1) + (a2 + a3)) / (float)cnt;

        // broadcast sp via LDS (wave-lockstep, no barrier)
        sp_lds[wave][lane] = (f16)spv;
        const f16x8* sp8 = (const f16x8*)&sp_lds[wave][0];
        float x0 = b, x1 = 0.f, x2 = 0.f, x3 = 0.f;
        #pragma unroll
        for (int c8 = 0; c8 < 8; ++c8) {
            const f16x8 v = sp8[c8];            // 1 ds_read_b128 broadcast
            const f16x8 d = dwr[c8];
            x0 = FDOT2(__builtin_shufflevector(v, v, 0, 1),
                       __builtin_shufflevector(d, d, 0, 1), x0);
            x1 = FDOT2(__builtin_shufflevector(v, v, 2, 3),
                       __builtin_shufflevector(d, d, 2, 3), x1);
            x2 = FDOT2(__builtin_shufflevector(v, v, 4, 5),
                       __builtin_shufflevector(d, d, 4, 5), x2);
            x3 = FDOT2(__builtin_shufflevector(v, v, 6, 7),
                       __builtin_shufflevector(d, d, 6, 7), x3);
        }
        float xv = fmaxf((x0 + x1) + (x2 + x3), 0.0f);

        xout[(size_t)n * COUT + lane] = xv;
        sum   += xv;
        sumsq += xv * xv;
    }

    red[0][wave][lane] = sum;
    red[1][wave][lane] = sumsq;
    __syncthreads();
    if (wave == 0) {
        float s = red[0][0][lane] + red[0][1][lane] + red[0][2][lane] + red[0][3][lane];
        float q = red[1][0][lane] + red[1][1][lane] + red[1][2][lane] + red[1][3][lane];
        atomicAdd(&stats[lane], s);
        atomicAdd(&stats[COUT + lane], q);
    }
}

// ---------------- kernel 2: finalize BN scale/shift -------------------
__global__ void k_finalize(const float* __restrict__ stats,
                           const float* __restrict__ gamma,
                           const float* __restrict__ beta,
                           float* __restrict__ sc_sh, float invN) {
    const int j = threadIdx.x;               // 64 threads
    const float mean = stats[j] * invN;
    const float var  = stats[COUT + j] * invN - mean * mean;
    const float s    = gamma[j] * rsqrtf(var + BN_EPS);
    sc_sh[j]        = s;
    sc_sh[COUT + j] = beta[j] - mean * s;
}

// ---------------- kernel 3: apply BN in place on d_out ----------------
__global__ __launch_bounds__(256) void k_apply(float* __restrict__ x,
                                               const float* __restrict__ sc_sh,
                                               int total4) {
    __shared__ float s[COUT], sh[COUT];
    if (threadIdx.x < COUT) {
        s[threadIdx.x]  = sc_sh[threadIdx.x];
        sh[threadIdx.x] = sc_sh[COUT + threadIdx.x];
    }
    __syncthreads();
    const int stride = gridDim.x * blockDim.x;
    for (int idx = blockIdx.x * blockDim.x + threadIdx.x; idx < total4; idx += stride) {
        float4 v = ((const float4*)x)[idx];
        const int j = (idx * 4) & (COUT - 1);
        v.x = fmaf(v.x, s[j],     sh[j]);
        v.y = fmaf(v.y, s[j + 1], sh[j + 1]);
        v.z = fmaf(v.z, s[j + 2], sh[j + 2]);
        v.w = fmaf(v.w, s[j + 3], sh[j + 3]);
        ((float4*)x)[idx] = v;
    }
}

extern "C" void kernel_launch(void* const* d_in, const int* in_sizes, int n_in,
                              void* d_out, int out_size, void* d_ws, size_t ws_size,
                              hipStream_t stream) {
    const float* inputs     = (const float*)d_in[0];
    const float* sw         = (const float*)d_in[1];
    const float* dw         = (const float*)d_in[2];
    const float* bias       = (const float*)d_in[3];
    const float* gamma      = (const float*)d_in[4];
    const float* beta       = (const float*)d_in[5];
    const int*   nn_count   = (const int*)d_in[6];
    const int*   nn_index   = (const int*)d_in[7];
    const int*   filt_index = (const int*)d_in[8];

    const int N = in_sizes[0] / CIN;           // 65536
    float* x     = (float*)d_out;

    // workspace layout (16B-aligned chunks)
    float* stats = (float*)d_ws;                         // 128 f
    float* sc_sh = (float*)d_ws + 128;                   // 128 f
    f16*   in_h  = (f16*)((float*)d_ws + 256);           // (N+1)*64 f16
    f16*   sw_h  = in_h + (size_t)(N + 1) * CIN;         // 27*64 f16
    f16*   dwp   = sw_h + NKERN * CIN + 32;              // pad to 16B, 8*64*8 f16

    k_zero<<<1, 128, 0, stream>>>(stats);
    k_cvt<<<2048, 256, 0, stream>>>(inputs, in_h, N * CIN / 4);
    k_prep<<<1, 256, 0, stream>>>(sw, dw, sw_h, dwp, in_h + (size_t)N * CIN);

    const int blocks = N / (4 * PPW);          // 2048
    k_conv<<<blocks, 256, 0, stream>>>(
        in_h, sw_h, dwp, bias, nn_count, nn_index, filt_index, x, stats, N);

    k_finalize<<<1, COUT, 0, stream>>>(stats, gamma, beta, sc_sh, 1.0f / (float)N);

    const int total4 = N * COUT / 4;
    k_apply<<<2048, 256, 0, stream>>>(x, sc_sh, total4);
}

// Round 9
// 106.332 us; speedup vs baseline: 1.3092x; 1.3092x over previous
//
#include <hip/hip_runtime.h>
#include <math.h>

#define KMAX   32
#define CIN    64
#define COUT   64
#define NKERN  27
#define GPW    8          // points per wave, gather kernel
#define MPW    32         // points per wave, matmul kernels
constexpr float BN_EPS = 1e-5f;

typedef _Float16 f16;
typedef _Float16 f16x2 __attribute__((ext_vector_type(2)));
typedef _Float16 f16x8 __attribute__((ext_vector_type(8)));

#if __has_builtin(__builtin_amdgcn_fdot2)
#define FDOT2(a, b, c) __builtin_amdgcn_fdot2((a), (b), (c), false)
#else
static __device__ inline float FDOT2(f16x2 a, f16x2 b, float c) {
    return fmaf((float)a.x, (float)b.x, fmaf((float)a.y, (float)b.y, c));
}
#endif

// ---------------- kernel P: zero stats + zeros-row --------------------
__global__ void k_prep(float* __restrict__ stats, f16* __restrict__ zrow) {
    const int t = threadIdx.x;          // 128 threads
    stats[t] = 0.0f;
    if (t < CIN) zrow[t] = (f16)0.0f;
}

// ---------------- kernel A: convert inputs f32 -> f16 -----------------
__global__ __launch_bounds__(256) void k_cvt(const float* __restrict__ in,
                                             f16* __restrict__ out, int total4) {
    const int stride = gridDim.x * blockDim.x;
    for (int i = blockIdx.x * blockDim.x + threadIdx.x; i < total4; i += stride) {
        const float4 v = ((const float4*)in)[i];
        f16x2 a = { (f16)v.x, (f16)v.y };
        f16x2 b = { (f16)v.z, (f16)v.w };
        uint2 u;
        u.x = *(const unsigned int*)&a;
        u.y = *(const unsigned int*)&b;
        ((uint2*)out)[i] = u;
    }
}

// ---------------- kernel G: PURE gather + spatial filter --------------
// Writes sp[n,c] (f16). No matmul, no stats: minimal live state so the
// 32-deep unconditional gather pipeline (zeros-row select, maskless FMA)
// can hold registers. sw stays in LDS (R4-proven).
__global__ __launch_bounds__(256, 4) void k_gather(
    const f16*   __restrict__ gh,          // f16[(N+1),64], row N = zeros
    const float* __restrict__ sw,          // [27,64]
    const int*   __restrict__ nn_count,    // [N]
    const int*   __restrict__ nn_index,    // [N,32]
    const int*   __restrict__ filt_index,  // [N,32]
    f16*         __restrict__ sp,          // [N,64] out
    int zrowIdx)                           // = N
{
    __shared__ float sw_lds[NKERN * CIN];  // 6.75 KB
    const int tid = threadIdx.x;
    for (int i = tid; i < NKERN * CIN; i += 256) sw_lds[i] = sw[i];
    __syncthreads();

    const int wave = tid >> 6;
    const int lane = tid & 63;
    const int base = blockIdx.x * (4 * GPW) + wave * GPW;

    for (int p = 0; p < GPW; ++p) {
        const int n   = base + p;
        const int cnt = nn_count[n];
        const int4* __restrict__ ni4 = (const int4*)(nn_index   + (size_t)n * KMAX);
        const int4* __restrict__ fi4 = (const int4*)(filt_index + (size_t)n * KMAX);

        int idx[32], flt[32];
        #pragma unroll
        for (int q = 0; q < 8; ++q) {
            *(int4*)&idx[4 * q] = ni4[q];
            *(int4*)&flt[4 * q] = fi4[q];
        }
        // invalid neighbors -> zeros row (same L1-resident line for all)
        #pragma unroll
        for (int k = 0; k < 32; ++k) idx[k] = (k < cnt) ? idx[k] : zrowIdx;

        f16 g[32];
        #pragma unroll
        for (int k = 0; k < 32; ++k)           // 32 independent gathers
            g[k] = gh[(size_t)idx[k] * CIN + lane];

        float a0 = 0.f, a1 = 0.f, a2 = 0.f, a3 = 0.f;
        #pragma unroll
        for (int k = 0; k < 32; ++k) {
            float& a = (k & 3) == 0 ? a0 : (k & 3) == 1 ? a1
                     : (k & 3) == 2 ? a2 : a3;
            a = fmaf((float)g[k], sw_lds[flt[k] * CIN + lane], a);
        }
        sp[(size_t)n * CIN + lane] = (f16)(((a0 + a1) + (a2 + a3)) / (float)cnt);
    }
}

// ---------------- shared matmul body (must be identical in both passes)
__device__ __forceinline__ float compute_x(const f16x8* __restrict__ sp8,
                                           const f16x2* __restrict__ dw_lds,
                                           int lane, float b) {
    float x0 = b, x1 = 0.f, x2 = 0.f, x3 = 0.f;
    #pragma unroll
    for (int c8 = 0; c8 < 8; ++c8) {
        const f16x8 v = sp8[c8];               // 1 ds_read_b128 broadcast
        x0 = FDOT2(__builtin_shufflevector(v, v, 0, 1),
                   dw_lds[(4 * c8 + 0) * COUT + lane], x0);
        x1 = FDOT2(__builtin_shufflevector(v, v, 2, 3),
                   dw_lds[(4 * c8 + 1) * COUT + lane], x1);
        x2 = FDOT2(__builtin_shufflevector(v, v, 4, 5),
                   dw_lds[(4 * c8 + 2) * COUT + lane], x2);
        x3 = FDOT2(__builtin_shufflevector(v, v, 6, 7),
                   dw_lds[(4 * c8 + 3) * COUT + lane], x3);
    }
    return fmaxf((x0 + x1) + (x2 + x3), 0.0f);
}

// stage dw (f32 global) -> LDS f16x2 [c2*COUT+j]
__device__ __forceinline__ void stage_dw(const float* __restrict__ dw,
                                         f16x2* __restrict__ dw_lds, int tid) {
    for (int i = tid; i < (CIN / 2) * COUT; i += 256) {
        const int c2 = i >> 6, j = i & 63;
        f16x2 w = { (f16)dw[(2 * c2) * COUT + j], (f16)dw[(2 * c2 + 1) * COUT + j] };
        dw_lds[i] = w;
    }
}

// ---------------- kernel M1: matmul + relu -> stats only --------------
__global__ __launch_bounds__(256, 4) void k_mm_stats(
    const f16*   __restrict__ sp,          // [N,64]
    const float* __restrict__ dw,          // [64,64]
    const float* __restrict__ bias,        // [1,64]
    float*       __restrict__ stats)       // [128]
{
    __shared__ f16x2 dw_lds[(CIN / 2) * COUT];   // 8 KB
    __shared__ f16   sp_lds[4][CIN];             // 0.5 KB
    __shared__ float red[2][4][COUT];            // 2 KB

    const int tid = threadIdx.x;
    stage_dw(dw, dw_lds, tid);
    __syncthreads();

    const int wave = tid >> 6;
    const int lane = tid & 63;
    const float b = bias[lane];
    const int base = blockIdx.x * (4 * MPW) + wave * MPW;
    float sum = 0.f, sumsq = 0.f;

    for (int p = 0; p < MPW; ++p) {
        const int n = base + p;
        sp_lds[wave][lane] = sp[(size_t)n * CIN + lane];   // wave-lockstep
        const float xv = compute_x((const f16x8*)&sp_lds[wave][0], dw_lds, lane, b);
        sum   += xv;
        sumsq += xv * xv;
    }

    red[0][wave][lane] = sum;
    red[1][wave][lane] = sumsq;
    __syncthreads();
    if (wave == 0) {
        float s = red[0][0][lane] + red[0][1][lane] + red[0][2][lane] + red[0][3][lane];
        float q = red[1][0][lane] + red[1][1][lane] + red[1][2][lane] + red[1][3][lane];
        atomicAdd(&stats[lane], s);
        atomicAdd(&stats[COUT + lane], q);
    }
}

// ---------------- kernel 2: finalize BN scale/shift -------------------
__global__ void k_finalize(const float* __restrict__ stats,
                           const float* __restrict__ gamma,
                           const float* __restrict__ beta,
                           float* __restrict__ sc_sh, float invN) {
    const int j = threadIdx.x;               // 64 threads
    const float mean = stats[j] * invN;
    const float var  = stats[COUT + j] * invN - mean * mean;
    const float s    = gamma[j] * rsqrtf(var + BN_EPS);
    sc_sh[j]        = s;
    sc_sh[COUT + j] = beta[j] - mean * s;
}

// ---------------- kernel M2: matmul + relu + BN -> d_out --------------
__global__ __launch_bounds__(256, 4) void k_mm_out(
    const f16*   __restrict__ sp,          // [N,64]
    const float* __restrict__ dw,          // [64,64]
    const float* __restrict__ bias,        // [1,64]
    const float* __restrict__ sc_sh,       // [128]
    float*       __restrict__ out)         // [N,64]
{
    __shared__ f16x2 dw_lds[(CIN / 2) * COUT];   // 8 KB
    __shared__ f16   sp_lds[4][CIN];             // 0.5 KB

    const int tid = threadIdx.x;
    stage_dw(dw, dw_lds, tid);
    __syncthreads();

    const int wave = tid >> 6;
    const int lane = tid & 63;
    const float b  = bias[lane];
    const float s  = sc_sh[lane];
    const float sh = sc_sh[COUT + lane];
    const int base = blockIdx.x * (4 * MPW) + wave * MPW;

    for (int p = 0; p < MPW; ++p) {
        const int n = base + p;
        sp_lds[wave][lane] = sp[(size_t)n * CIN + lane];   // wave-lockstep
        const float xv = compute_x((const f16x8*)&sp_lds[wave][0], dw_lds, lane, b);
        out[(size_t)n * COUT + lane] = fmaf(xv, s, sh);
    }
}

extern "C" void kernel_launch(void* const* d_in, const int* in_sizes, int n_in,
                              void* d_out, int out_size, void* d_ws, size_t ws_size,
                              hipStream_t stream) {
    const float* inputs     = (const float*)d_in[0];
    const float* sw         = (const float*)d_in[1];
    const float* dw         = (const float*)d_in[2];
    const float* bias       = (const float*)d_in[3];
    const float* gamma      = (const float*)d_in[4];
    const float* beta       = (const float*)d_in[5];
    const int*   nn_count   = (const int*)d_in[6];
    const int*   nn_index   = (const int*)d_in[7];
    const int*   filt_index = (const int*)d_in[8];

    const int N = in_sizes[0] / CIN;           // 65536
    float* out   = (float*)d_out;

    // ws layout: stats(128f) | sc_sh(128f) | in_h((N+1)*64 f16) | sp(N*64 f16)
    float* stats = (float*)d_ws;
    float* sc_sh = (float*)d_ws + 128;
    f16*   in_h  = (f16*)((float*)d_ws + 256);
    f16*   spb   = in_h + (size_t)(N + 1) * CIN;

    k_prep<<<1, 128, 0, stream>>>(stats, in_h + (size_t)N * CIN);
    k_cvt<<<2048, 256, 0, stream>>>(inputs, in_h, N * CIN / 4);

    k_gather<<<N / (4 * GPW), 256, 0, stream>>>(
        in_h, sw, nn_count, nn_index, filt_index, spb, N);

    k_mm_stats<<<N / (4 * MPW), 256, 0, stream>>>(spb, dw, bias, stats);
    k_finalize<<<1, COUT, 0, stream>>>(stats, gamma, beta, sc_sh, 1.0f / (float)N);
    k_mm_out<<<N / (4 * MPW), 256, 0, stream>>>(spb, dw, bias, sc_sh, out);
}